// Round 7
// baseline (366.607 us; speedup 1.0000x reference)
//
#include <hip/hip_runtime.h>
#include <hip/hip_bf16.h>
#include <math.h>

constexpr int IN_DIM = 512;
constexpr int HID = 64;
constexpr int OUTD = 40;
constexpr int SCAN_CHUNK = 1024;

typedef __attribute__((ext_vector_type(8))) short bf16x8;
typedef __attribute__((ext_vector_type(4))) float floatx4;
typedef unsigned short ushort_t;

__device__ __forceinline__ unsigned short f2bf(float f) {
    unsigned u = __float_as_uint(f);
    u += 0x7fff + ((u >> 16) & 1);
    return (unsigned short)(u >> 16);
}

__device__ __forceinline__ unsigned pk2(float x, float y) {
    __hip_bfloat162 h = __float22bfloat162_rn(make_float2(x, y));
    return *reinterpret_cast<unsigned*>(&h);
}

// ---------------- W1 transpose+convert: Wt[(c32*64+n)*32 + (k&31)] ----------------
__global__ __launch_bounds__(256) void w1t_kernel(const float* __restrict__ W1,
                                                  ushort_t* __restrict__ Wt) {
    int tid = blockIdx.x * 256 + threadIdx.x;
    int k = tid >> 6;
    int n = tid & 63;
    Wt[(size_t)((k >> 5) * 64 + n) * 32 + (k & 31)] = f2bf(W1[tid]);
}

// ---------------- GEMM1 v3: LDS-staged A (coalesced), K-split x2 ----------------
// Block = 32 rows, 4 waves = 2 row-groups x 2 K-halves. BK=64 chunks, stride-68 pad.
__global__ __launch_bounds__(256, 6) void gemm1_kernel(const float* __restrict__ x,
                                                       const ushort_t* __restrict__ Wt,
                                                       ushort_t* __restrict__ h1b, int N) {
    __shared__ float As[2][32 * 68];  // [kh][row*68 + col], 272B row stride (16B aligned)
    const int lane = threadIdx.x & 63;
    const int wave = threadIdx.x >> 6;
    const int g = wave & 1;    // row group (16 rows)
    const int kh = wave >> 1;  // K half (256 floats)
    const int lm = lane & 15;
    const int quad = lane >> 4;
    const int row0 = blockIdx.x * 32;

    floatx4 acc0 = {0.f, 0.f, 0.f, 0.f};
    floatx4 acc1 = {0.f, 0.f, 0.f, 0.f};
    floatx4 acc2 = {0.f, 0.f, 0.f, 0.f};
    floatx4 acc3 = {0.f, 0.f, 0.f, 0.f};

    const ushort_t* wb = Wt + lm * 32 + quad * 8;

    for (int ch = 0; ch < 4; ++ch) {
        // Stage this kh-half's 32x64 tile; the 2 waves sharing kh split the 512 float4 slots.
#pragma unroll
        for (int i = 0; i < 4; ++i) {
            int s = g * 64 + lane + i * 128;  // 0..511
            int r = s >> 4;
            int kq = s & 15;
            int grow = row0 + r;
            float4 v = make_float4(0.f, 0.f, 0.f, 0.f);
            if (grow < N)
                v = *(const float4*)&x[(size_t)grow * IN_DIM + kh * 256 + ch * 64 + kq * 4];
            *(float4*)&As[kh][r * 68 + kq * 4] = v;
        }
        __syncthreads();
#pragma unroll
        for (int cc = 0; cc < 2; ++cc) {
            const float* ap = &As[kh][(g * 16 + lm) * 68 + cc * 32 + quad * 8];
            float4 a0 = *(const float4*)ap;
            float4 a1 = *(const float4*)(ap + 4);
            union { bf16x8 v; unsigned u[4]; } af;
            af.u[0] = pk2(a0.x, a0.y);
            af.u[1] = pk2(a0.z, a0.w);
            af.u[2] = pk2(a1.x, a1.y);
            af.u[3] = pk2(a1.z, a1.w);

            const ushort_t* wc = wb + (size_t)(kh * 8 + ch * 2 + cc) * 2048;
            bf16x8 b0 = *(const bf16x8*)(wc);
            bf16x8 b1 = *(const bf16x8*)(wc + 512);
            bf16x8 b2 = *(const bf16x8*)(wc + 1024);
            bf16x8 b3 = *(const bf16x8*)(wc + 1536);

            acc0 = __builtin_amdgcn_mfma_f32_16x16x32_bf16(af.v, b0, acc0, 0, 0, 0);
            acc1 = __builtin_amdgcn_mfma_f32_16x16x32_bf16(af.v, b1, acc1, 0, 0, 0);
            acc2 = __builtin_amdgcn_mfma_f32_16x16x32_bf16(af.v, b2, acc2, 0, 0, 0);
            acc3 = __builtin_amdgcn_mfma_f32_16x16x32_bf16(af.v, b3, acc3, 0, 0, 0);
        }
        __syncthreads();
    }

    // Cross-K-half reduce via LDS (reuse As). Stride 20 floats keeps 16B alignment.
    float* red = &As[0][0];
    if (kh == 1) {
        *(floatx4*)&red[((g * 4 + 0) * 16 + lm) * 20 + quad * 4] = acc0;
        *(floatx4*)&red[((g * 4 + 1) * 16 + lm) * 20 + quad * 4] = acc1;
        *(floatx4*)&red[((g * 4 + 2) * 16 + lm) * 20 + quad * 4] = acc2;
        *(floatx4*)&red[((g * 4 + 3) * 16 + lm) * 20 + quad * 4] = acc3;
    }
    __syncthreads();
    if (kh == 0) {
        acc0 += *(const floatx4*)&red[((g * 4 + 0) * 16 + lm) * 20 + quad * 4];
        acc1 += *(const floatx4*)&red[((g * 4 + 1) * 16 + lm) * 20 + quad * 4];
        acc2 += *(const floatx4*)&red[((g * 4 + 2) * 16 + lm) * 20 + quad * 4];
        acc3 += *(const floatx4*)&red[((g * 4 + 3) * 16 + lm) * 20 + quad * 4];
        const int r0 = row0 + g * 16 + quad * 4;
#pragma unroll
        for (int reg = 0; reg < 4; ++reg) {
            int r = r0 + reg;
            if (r < N) {
                ushort_t* hr = h1b + (size_t)r * HID + lm;
                hr[0]  = f2bf(acc0[reg]);
                hr[16] = f2bf(acc1[reg]);
                hr[32] = f2bf(acc2[reg]);
                hr[48] = f2bf(acc3[reg]);
            }
        }
    }
}

// ---------------- CSR build ----------------
__global__ __launch_bounds__(256) void deg_kernel(const int* __restrict__ dst,
                                                  int* __restrict__ deg, int E) {
    int e = blockIdx.x * 256 + threadIdx.x;
    if (e < E) atomicAdd(&deg[dst[e]], 1);
}

__global__ __launch_bounds__(256) void scanA_kernel(const int* __restrict__ deg,
                                                    int* __restrict__ blockSums, int N) {
    __shared__ int sm[256];
    const int t = threadIdx.x;
    const int base = blockIdx.x * SCAN_CHUNK + t * 4;
    int s = 0;
    if (base + 3 < N) {
        int4 v = *(const int4*)&deg[base];
        s = v.x + v.y + v.z + v.w;
    } else {
#pragma unroll
        for (int i = 0; i < 4; ++i)
            if (base + i < N) s += deg[base + i];
    }
    sm[t] = s;
    __syncthreads();
    for (int off = 128; off; off >>= 1) {
        if (t < off) sm[t] += sm[t + off];
        __syncthreads();
    }
    if (t == 0) blockSums[blockIdx.x] = sm[0];
}

__global__ __launch_bounds__(256) void scanB_kernel(int* __restrict__ blockSums, int nb) {
    __shared__ int sm[256];
    const int t = threadIdx.x;
    int v = (t < nb) ? blockSums[t] : 0;
    sm[t] = v;
    __syncthreads();
    for (int off = 1; off < 256; off <<= 1) {
        int u = (t >= off) ? sm[t - off] : 0;
        __syncthreads();
        sm[t] += u;
        __syncthreads();
    }
    if (t < nb) blockSums[t] = sm[t] - v;
}

__global__ __launch_bounds__(256) void scanC_kernel(const int* __restrict__ deg,
                                                    const int* __restrict__ blockSums,
                                                    int* __restrict__ rowptr,
                                                    int* __restrict__ cursor, int N, int E) {
    __shared__ int sm[256];
    const int t = threadIdx.x;
    const int base = blockIdx.x * SCAN_CHUNK + t * 4;
    int v[4] = {0, 0, 0, 0};
    if (base + 3 < N) {
        int4 q = *(const int4*)&deg[base];
        v[0] = q.x; v[1] = q.y; v[2] = q.z; v[3] = q.w;
    } else {
#pragma unroll
        for (int i = 0; i < 4; ++i)
            if (base + i < N) v[i] = deg[base + i];
    }
    int s = v[0] + v[1] + v[2] + v[3];
    sm[t] = s;
    __syncthreads();
    for (int off = 1; off < 256; off <<= 1) {
        int u = (t >= off) ? sm[t - off] : 0;
        __syncthreads();
        sm[t] += u;
        __syncthreads();
    }
    int run = blockSums[blockIdx.x] + sm[t] - s;
#pragma unroll
    for (int i = 0; i < 4; ++i) {
        int idx = base + i;
        if (idx < N) {
            rowptr[idx] = run;
            cursor[idx] = run;
            run += v[i];
        }
    }
    if (blockIdx.x == 0 && t == 0) rowptr[N] = E;
}

__global__ __launch_bounds__(256) void fill_kernel(const int* __restrict__ src,
                                                   const int* __restrict__ dst,
                                                   int* __restrict__ cursor,
                                                   int* __restrict__ srcs, int E) {
    int e = blockIdx.x * 256 + threadIdx.x;
    if (e < E) {
        int pos = atomicAdd(&cursor[dst[e]], 1);
        srcs[pos] = src[e];
    }
}

// ---------------- Gather-agg 1 + ReLU, output bf16: agg1b = relu(A . h1) ----------------
__global__ __launch_bounds__(256) void agg1_kernel(const ushort_t* __restrict__ h1b,
                                                   const int* __restrict__ rowptr,
                                                   const int* __restrict__ srcs,
                                                   ushort_t* __restrict__ agg1b, int N) {
    int node = (blockIdx.x * 256 + threadIdx.x) >> 6;
    int lane = threadIdx.x & 63;
    if (node >= N) return;
    int b = rowptr[node], e = rowptr[node + 1];
    const int half = lane >> 5;
    const int cp = lane & 31;
    float acc0 = 0.f, acc1 = 0.f;
    for (int j = b; j < e; j += 8) {
        int i0 = j + half * 4;
        unsigned u[4] = {0u, 0u, 0u, 0u};
#pragma unroll
        for (int t = 0; t < 4; ++t) {
            int it = i0 + t;
            if (it < e) {
                int s = srcs[it];
                u[t] = *(const unsigned*)&h1b[(size_t)s * HID + cp * 2];
            }
        }
#pragma unroll
        for (int t = 0; t < 4; ++t) {
            acc0 += __uint_as_float(u[t] << 16);
            acc1 += __uint_as_float(u[t] & 0xffff0000u);
        }
    }
    acc0 += __shfl_xor(acc0, 32, 64);
    acc1 += __shfl_xor(acc1, 32, 64);
    if (half == 0) {
        *(unsigned*)&agg1b[(size_t)node * HID + cp * 2] =
            pk2(fmaxf(acc0, 0.f), fmaxf(acc1, 0.f));
    }
}

// ---------------- Layer 2 fused: gather(agg1b) -> @W2 -> log_softmax ----------------
// Uses (A . relu(g1)) @ W2 == A . (relu(g1) @ W2). One wave per node.
__global__ __launch_bounds__(256) void agg2_lsm_kernel(const ushort_t* __restrict__ agg1b,
                                                       const int* __restrict__ rowptr,
                                                       const int* __restrict__ srcs,
                                                       const float* __restrict__ W2,
                                                       float* __restrict__ out, int N) {
    __shared__ float W2s[HID * OUTD];  // 10.2 KB
    __shared__ float gbuf[4][HID];
    for (int i = threadIdx.x; i < HID * OUTD; i += 256) W2s[i] = W2[i];

    int node = (blockIdx.x * 256 + threadIdx.x) >> 6;
    int lane = threadIdx.x & 63;
    int wv = threadIdx.x >> 6;
    const bool nodeOK = node < N;
    int b = 0, e = 0;
    if (nodeOK) { b = rowptr[node]; e = rowptr[node + 1]; }
    const int half = lane >> 5;
    const int cp = lane & 31;
    float acc0 = 0.f, acc1 = 0.f;
    for (int j = b; j < e; j += 8) {
        int i0 = j + half * 4;
        unsigned u[4] = {0u, 0u, 0u, 0u};
#pragma unroll
        for (int t = 0; t < 4; ++t) {
            int it = i0 + t;
            if (it < e) {
                int s = srcs[it];
                u[t] = *(const unsigned*)&agg1b[(size_t)s * HID + cp * 2];
            }
        }
#pragma unroll
        for (int t = 0; t < 4; ++t) {
            acc0 += __uint_as_float(u[t] << 16);
            acc1 += __uint_as_float(u[t] & 0xffff0000u);
        }
    }
    acc0 += __shfl_xor(acc0, 32, 64);
    acc1 += __shfl_xor(acc1, 32, 64);
    if (half == 0)
        *(float2*)&gbuf[wv][cp * 2] = make_float2(acc0, acc1);
    __syncthreads();  // covers W2s staging + gbuf writes (all waves reach it)

    // z[j] = sum_k gbuf[wv][k] * W2s[k*40+j], j = lane (<40)
    float z = 0.f;
    if (lane < OUTD) {
#pragma unroll 4
        for (int k = 0; k < HID; ++k)
            z = fmaf(gbuf[wv][k], W2s[k * OUTD + lane], z);
    }
    float v = (lane < OUTD) ? z : -INFINITY;
    float m = v;
#pragma unroll
    for (int o = 32; o; o >>= 1) m = fmaxf(m, __shfl_xor(m, o, 64));
    float ex = (lane < OUTD) ? expf(v - m) : 0.f;
    float s = ex;
#pragma unroll
    for (int o = 32; o; o >>= 1) s += __shfl_xor(s, o, 64);
    if (nodeOK && lane < OUTD)
        out[(size_t)node * OUTD + lane] = v - m - logf(s);
}

extern "C" void kernel_launch(void* const* d_in, const int* in_sizes, int n_in,
                              void* d_out, int out_size, void* d_ws, size_t ws_size,
                              hipStream_t stream) {
    const float* x  = (const float*)d_in[0];
    const int*  src = (const int*)d_in[1];
    const int*  dst = (const int*)d_in[2];
    const float* W1 = (const float*)d_in[3];
    const float* W2 = (const float*)d_in[4];
    float* out = (float*)d_out;

    const int N = in_sizes[0] / IN_DIM;   // 50000
    const int E = in_sizes[1];            // 800000

    char* base = (char*)d_ws;
    ushort_t* Wt    = (ushort_t*)base;                      // 64 KB
    ushort_t* h1b   = (ushort_t*)(base + 65536);            // N*64 bf16
    ushort_t* agg1b = h1b + (size_t)N * HID;                // N*64 bf16
    int*   deg      = (int*)(agg1b + (size_t)N * HID);      // N
    int*   rowptr   = deg + N;                              // N+1
    int*   cursor   = rowptr + N + 1;                       // N
    int*   blockSums = cursor + N;                          // <=256
    int*   srcs     = blockSums + 256;                      // E

    const int nScanBlocks = (N + SCAN_CHUNK - 1) / SCAN_CHUNK;

    hipMemsetAsync(deg, 0, (size_t)N * sizeof(int), stream);

    w1t_kernel<<<(IN_DIM * HID) / 256, 256, 0, stream>>>(W1, Wt);
    gemm1_kernel<<<(N + 31) / 32, 256, 0, stream>>>(x, Wt, h1b, N);

    deg_kernel<<<(E + 255) / 256, 256, 0, stream>>>(dst, deg, E);
    scanA_kernel<<<nScanBlocks, 256, 0, stream>>>(deg, blockSums, N);
    scanB_kernel<<<1, 256, 0, stream>>>(blockSums, nScanBlocks);
    scanC_kernel<<<nScanBlocks, 256, 0, stream>>>(deg, blockSums, rowptr, cursor, N, E);
    fill_kernel<<<(E + 255) / 256, 256, 0, stream>>>(src, dst, cursor, srcs, E);

    agg1_kernel<<<(N * 64 + 255) / 256, 256, 0, stream>>>(h1b, rowptr, srcs, agg1b, N);
    agg2_lsm_kernel<<<(N * 64 + 255) / 256, 256, 0, stream>>>(agg1b, rowptr, srcs, W2, out, N);
}

// Round 8
// 336.959 us; speedup vs baseline: 1.0880x; 1.0880x over previous
//
#include <hip/hip_runtime.h>
#include <hip/hip_bf16.h>
#include <math.h>

constexpr int IN_DIM = 512;
constexpr int HID = 64;
constexpr int OUTD = 40;
constexpr int SCAN_CHUNK = 1024;

typedef __attribute__((ext_vector_type(8))) short bf16x8;
typedef __attribute__((ext_vector_type(4))) float floatx4;
typedef unsigned short ushort_t;

__device__ __forceinline__ unsigned short f2bf(float f) {
    unsigned u = __float_as_uint(f);
    u += 0x7fff + ((u >> 16) & 1);
    return (unsigned short)(u >> 16);
}

__device__ __forceinline__ unsigned pk2(float x, float y) {
    __hip_bfloat162 h = __float22bfloat162_rn(make_float2(x, y));
    return *reinterpret_cast<unsigned*>(&h);
}

// ---------------- merged: W1 transpose+convert (blocks 0..127) | deg histogram ----------------
__global__ __launch_bounds__(256) void w1t_deg_kernel(const float* __restrict__ W1,
                                                      ushort_t* __restrict__ Wt,
                                                      const int* __restrict__ dst,
                                                      int* __restrict__ deg, int E) {
    int bid = blockIdx.x;
    if (bid < 128) {
        int tid = bid * 256 + threadIdx.x;  // 0..32767
        int k = tid >> 6;
        int n = tid & 63;
        Wt[(size_t)((k >> 5) * 64 + n) * 32 + (k & 31)] = f2bf(W1[tid]);
    } else {
        int e = (bid - 128) * 256 + threadIdx.x;
        if (e < E) atomicAdd(&deg[dst[e]], 1);
    }
}

// ---------------- GEMM1 v3: LDS-staged A (coalesced), K-split x2 ----------------
__global__ __launch_bounds__(256, 6) void gemm1_kernel(const float* __restrict__ x,
                                                       const ushort_t* __restrict__ Wt,
                                                       ushort_t* __restrict__ h1b, int N) {
    __shared__ float As[2][32 * 68];
    const int lane = threadIdx.x & 63;
    const int wave = threadIdx.x >> 6;
    const int g = wave & 1;
    const int kh = wave >> 1;
    const int lm = lane & 15;
    const int quad = lane >> 4;
    const int row0 = blockIdx.x * 32;

    floatx4 acc0 = {0.f, 0.f, 0.f, 0.f};
    floatx4 acc1 = {0.f, 0.f, 0.f, 0.f};
    floatx4 acc2 = {0.f, 0.f, 0.f, 0.f};
    floatx4 acc3 = {0.f, 0.f, 0.f, 0.f};

    const ushort_t* wb = Wt + lm * 32 + quad * 8;

    for (int ch = 0; ch < 4; ++ch) {
#pragma unroll
        for (int i = 0; i < 4; ++i) {
            int s = g * 64 + lane + i * 128;
            int r = s >> 4;
            int kq = s & 15;
            int grow = row0 + r;
            float4 v = make_float4(0.f, 0.f, 0.f, 0.f);
            if (grow < N)
                v = *(const float4*)&x[(size_t)grow * IN_DIM + kh * 256 + ch * 64 + kq * 4];
            *(float4*)&As[kh][r * 68 + kq * 4] = v;
        }
        __syncthreads();
#pragma unroll
        for (int cc = 0; cc < 2; ++cc) {
            const float* ap = &As[kh][(g * 16 + lm) * 68 + cc * 32 + quad * 8];
            float4 a0 = *(const float4*)ap;
            float4 a1 = *(const float4*)(ap + 4);
            union { bf16x8 v; unsigned u[4]; } af;
            af.u[0] = pk2(a0.x, a0.y);
            af.u[1] = pk2(a0.z, a0.w);
            af.u[2] = pk2(a1.x, a1.y);
            af.u[3] = pk2(a1.z, a1.w);

            const ushort_t* wc = wb + (size_t)(kh * 8 + ch * 2 + cc) * 2048;
            bf16x8 b0 = *(const bf16x8*)(wc);
            bf16x8 b1 = *(const bf16x8*)(wc + 512);
            bf16x8 b2 = *(const bf16x8*)(wc + 1024);
            bf16x8 b3 = *(const bf16x8*)(wc + 1536);

            acc0 = __builtin_amdgcn_mfma_f32_16x16x32_bf16(af.v, b0, acc0, 0, 0, 0);
            acc1 = __builtin_amdgcn_mfma_f32_16x16x32_bf16(af.v, b1, acc1, 0, 0, 0);
            acc2 = __builtin_amdgcn_mfma_f32_16x16x32_bf16(af.v, b2, acc2, 0, 0, 0);
            acc3 = __builtin_amdgcn_mfma_f32_16x16x32_bf16(af.v, b3, acc3, 0, 0, 0);
        }
        __syncthreads();
    }

    float* red = &As[0][0];
    if (kh == 1) {
        *(floatx4*)&red[((g * 4 + 0) * 16 + lm) * 20 + quad * 4] = acc0;
        *(floatx4*)&red[((g * 4 + 1) * 16 + lm) * 20 + quad * 4] = acc1;
        *(floatx4*)&red[((g * 4 + 2) * 16 + lm) * 20 + quad * 4] = acc2;
        *(floatx4*)&red[((g * 4 + 3) * 16 + lm) * 20 + quad * 4] = acc3;
    }
    __syncthreads();
    if (kh == 0) {
        acc0 += *(const floatx4*)&red[((g * 4 + 0) * 16 + lm) * 20 + quad * 4];
        acc1 += *(const floatx4*)&red[((g * 4 + 1) * 16 + lm) * 20 + quad * 4];
        acc2 += *(const floatx4*)&red[((g * 4 + 2) * 16 + lm) * 20 + quad * 4];
        acc3 += *(const floatx4*)&red[((g * 4 + 3) * 16 + lm) * 20 + quad * 4];
        const int r0 = row0 + g * 16 + quad * 4;
#pragma unroll
        for (int reg = 0; reg < 4; ++reg) {
            int r = r0 + reg;
            if (r < N) {
                ushort_t* hr = h1b + (size_t)r * HID + lm;
                hr[0]  = f2bf(acc0[reg]);
                hr[16] = f2bf(acc1[reg]);
                hr[32] = f2bf(acc2[reg]);
                hr[48] = f2bf(acc3[reg]);
            }
        }
    }
}

// ---------------- CSR scan ----------------
__global__ __launch_bounds__(256) void scanA_kernel(const int* __restrict__ deg,
                                                    int* __restrict__ blockSums, int N) {
    __shared__ int sm[256];
    const int t = threadIdx.x;
    const int base = blockIdx.x * SCAN_CHUNK + t * 4;
    int s = 0;
    if (base + 3 < N) {
        int4 v = *(const int4*)&deg[base];
        s = v.x + v.y + v.z + v.w;
    } else {
#pragma unroll
        for (int i = 0; i < 4; ++i)
            if (base + i < N) s += deg[base + i];
    }
    sm[t] = s;
    __syncthreads();
    for (int off = 128; off; off >>= 1) {
        if (t < off) sm[t] += sm[t + off];
        __syncthreads();
    }
    if (t == 0) blockSums[blockIdx.x] = sm[0];
}

__global__ __launch_bounds__(256) void scanB_kernel(int* __restrict__ blockSums, int nb) {
    __shared__ int sm[256];
    const int t = threadIdx.x;
    int v = (t < nb) ? blockSums[t] : 0;
    sm[t] = v;
    __syncthreads();
    for (int off = 1; off < 256; off <<= 1) {
        int u = (t >= off) ? sm[t - off] : 0;
        __syncthreads();
        sm[t] += u;
        __syncthreads();
    }
    if (t < nb) blockSums[t] = sm[t] - v;
}

__global__ __launch_bounds__(256) void scanC_kernel(const int* __restrict__ deg,
                                                    const int* __restrict__ blockSums,
                                                    int* __restrict__ rowptr,
                                                    int* __restrict__ cursor, int N, int E) {
    __shared__ int sm[256];
    const int t = threadIdx.x;
    const int base = blockIdx.x * SCAN_CHUNK + t * 4;
    int v[4] = {0, 0, 0, 0};
    if (base + 3 < N) {
        int4 q = *(const int4*)&deg[base];
        v[0] = q.x; v[1] = q.y; v[2] = q.z; v[3] = q.w;
    } else {
#pragma unroll
        for (int i = 0; i < 4; ++i)
            if (base + i < N) v[i] = deg[base + i];
    }
    int s = v[0] + v[1] + v[2] + v[3];
    sm[t] = s;
    __syncthreads();
    for (int off = 1; off < 256; off <<= 1) {
        int u = (t >= off) ? sm[t - off] : 0;
        __syncthreads();
        sm[t] += u;
        __syncthreads();
    }
    int run = blockSums[blockIdx.x] + sm[t] - s;
#pragma unroll
    for (int i = 0; i < 4; ++i) {
        int idx = base + i;
        if (idx < N) {
            rowptr[idx] = run;
            cursor[idx] = run;
            run += v[i];
        }
    }
    if (blockIdx.x == 0 && t == 0) rowptr[N] = E;
}

__global__ __launch_bounds__(256) void fill_kernel(const int* __restrict__ src,
                                                   const int* __restrict__ dst,
                                                   int* __restrict__ cursor,
                                                   int* __restrict__ srcs, int E) {
    int e = blockIdx.x * 256 + threadIdx.x;
    if (e < E) {
        int pos = atomicAdd(&cursor[dst[e]], 1);
        srcs[pos] = src[e];
    }
}

// ---------------- Gather-agg 1 + ReLU -> bf16 ----------------
__global__ __launch_bounds__(256) void agg1_kernel(const ushort_t* __restrict__ h1b,
                                                   const int* __restrict__ rowptr,
                                                   const int* __restrict__ srcs,
                                                   ushort_t* __restrict__ agg1b, int N) {
    int node = (blockIdx.x * 256 + threadIdx.x) >> 6;
    int lane = threadIdx.x & 63;
    if (node >= N) return;
    int b = rowptr[node], e = rowptr[node + 1];
    const int half = lane >> 5;
    const int cp = lane & 31;
    float acc0 = 0.f, acc1 = 0.f;
    for (int j = b; j < e; j += 8) {
        int i0 = j + half * 4;
        unsigned u[4] = {0u, 0u, 0u, 0u};
#pragma unroll
        for (int t = 0; t < 4; ++t) {
            int it = i0 + t;
            if (it < e) {
                int s = srcs[it];
                u[t] = *(const unsigned*)&h1b[(size_t)s * HID + cp * 2];
            }
        }
#pragma unroll
        for (int t = 0; t < 4; ++t) {
            acc0 += __uint_as_float(u[t] << 16);
            acc1 += __uint_as_float(u[t] & 0xffff0000u);
        }
    }
    acc0 += __shfl_xor(acc0, 32, 64);
    acc1 += __shfl_xor(acc1, 32, 64);
    if (half == 0) {
        *(unsigned*)&agg1b[(size_t)node * HID + cp * 2] =
            pk2(fmaxf(acc0, 0.f), fmaxf(acc1, 0.f));
    }
}

// ---------------- GEMM2: h2b = agg1b(bf16, relu'd) @ W2, output bf16 ----------------
__global__ __launch_bounds__(256) void gemm2_kernel(const ushort_t* __restrict__ agg1b,
                                                    const float* __restrict__ W2,
                                                    ushort_t* __restrict__ h2b, int N) {
    __shared__ float W2s[HID * OUTD];
    for (int i = threadIdx.x; i < HID * OUTD; i += 256) W2s[i] = W2[i];
    __syncthreads();
    int tid = blockIdx.x * 256 + threadIdx.x;
    if (tid >= N * 5) return;
    int row = tid / 5;
    int c0 = (tid - row * 5) * 8;
    const ushort_t* arow = &agg1b[(size_t)row * HID];
    float acc[8] = {};
#pragma unroll
    for (int k8 = 0; k8 < 8; ++k8) {
        uint4 q = *(const uint4*)&arow[k8 * 8];
        unsigned uu[4] = {q.x, q.y, q.z, q.w};
#pragma unroll
        for (int p = 0; p < 4; ++p) {
            float a0 = __uint_as_float(uu[p] << 16);
            float a1 = __uint_as_float(uu[p] & 0xffff0000u);
            int k = k8 * 8 + p * 2;
            const float* w0 = &W2s[k * OUTD + c0];
            const float* w1 = &W2s[(k + 1) * OUTD + c0];
#pragma unroll
            for (int j = 0; j < 8; ++j) acc[j] = fmaf(a0, w0[j], acc[j]);
#pragma unroll
            for (int j = 0; j < 8; ++j) acc[j] = fmaf(a1, w1[j], acc[j]);
        }
    }
    uint4 p;
    p.x = pk2(acc[0], acc[1]);
    p.y = pk2(acc[2], acc[3]);
    p.z = pk2(acc[4], acc[5]);
    p.w = pk2(acc[6], acc[7]);
    *(uint4*)&h2b[(size_t)row * OUTD + c0] = p;
}

// ---------------- Gather-agg 2 + log_softmax (h2b, 12 edges/iter, 4 chains) ----------------
__global__ __launch_bounds__(256) void agg2_lsm_kernel(const ushort_t* __restrict__ h2b,
                                                       const int* __restrict__ rowptr,
                                                       const int* __restrict__ srcs,
                                                       float* __restrict__ out, int N) {
    int node = (blockIdx.x * 256 + threadIdx.x) >> 6;
    int lane = threadIdx.x & 63;
    if (node >= N) return;
    int b = rowptr[node], e = rowptr[node + 1];
    const int trip = lane / 20;  // 0..3 (trip 3 idle)
    const int cp = lane % 20;
    const bool act = trip < 3;
    float acc0 = 0.f, acc1 = 0.f;
    for (int j = b; j < e; j += 12) {
        int i0 = j + trip * 4;
        unsigned u[4] = {0u, 0u, 0u, 0u};
#pragma unroll
        for (int t = 0; t < 4; ++t) {
            int it = i0 + t;
            if (act && it < e) {
                int s = srcs[it];
                u[t] = *(const unsigned*)&h2b[(size_t)s * OUTD + cp * 2];
            }
        }
#pragma unroll
        for (int t = 0; t < 4; ++t) {
            acc0 += __uint_as_float(u[t] << 16);
            acc1 += __uint_as_float(u[t] & 0xffff0000u);
        }
    }
    acc0 += __shfl(acc0, lane + 20, 64) + __shfl(acc0, lane + 40, 64);
    acc1 += __shfl(acc1, lane + 20, 64) + __shfl(acc1, lane + 40, 64);
    const bool lead = lane < 20;
    float m = lead ? fmaxf(acc0, acc1) : -INFINITY;
#pragma unroll
    for (int o = 16; o; o >>= 1) m = fmaxf(m, __shfl_xor(m, o, 64));
    float ex = lead ? (expf(acc0 - m) + expf(acc1 - m)) : 0.f;
#pragma unroll
    for (int o = 16; o; o >>= 1) ex += __shfl_xor(ex, o, 64);
    if (lead) {
        float ls = logf(ex);
        *(float2*)&out[(size_t)node * OUTD + cp * 2] =
            make_float2(acc0 - m - ls, acc1 - m - ls);
    }
}

extern "C" void kernel_launch(void* const* d_in, const int* in_sizes, int n_in,
                              void* d_out, int out_size, void* d_ws, size_t ws_size,
                              hipStream_t stream) {
    const float* x  = (const float*)d_in[0];
    const int*  src = (const int*)d_in[1];
    const int*  dst = (const int*)d_in[2];
    const float* W1 = (const float*)d_in[3];
    const float* W2 = (const float*)d_in[4];
    float* out = (float*)d_out;

    const int N = in_sizes[0] / IN_DIM;   // 50000
    const int E = in_sizes[1];            // 800000

    char* base = (char*)d_ws;
    ushort_t* Wt    = (ushort_t*)base;                      // 64 KB
    ushort_t* h1b   = (ushort_t*)(base + 65536);            // N*64 bf16
    ushort_t* agg1b = h1b + (size_t)N * HID;                // N*64 bf16
    ushort_t* h2b   = agg1b + (size_t)N * HID;              // N*40 bf16
    int*   deg      = (int*)(h2b + (size_t)N * OUTD);       // N  (N*40*2 divisible by 4? 80N yes)
    int*   rowptr   = deg + N;                              // N+1
    int*   cursor   = rowptr + N + 1;                       // N
    int*   blockSums = cursor + N;                          // <=256
    int*   srcs     = blockSums + 256;                      // E

    const int nScanBlocks = (N + SCAN_CHUNK - 1) / SCAN_CHUNK;

    hipMemsetAsync(deg, 0, (size_t)N * sizeof(int), stream);

    // merged W1-transpose + degree histogram
    w1t_deg_kernel<<<128 + (E + 255) / 256, 256, 0, stream>>>(W1, Wt, dst, deg, E);
    gemm1_kernel<<<(N + 31) / 32, 256, 0, stream>>>(x, Wt, h1b, N);

    scanA_kernel<<<nScanBlocks, 256, 0, stream>>>(deg, blockSums, N);
    scanB_kernel<<<1, 256, 0, stream>>>(blockSums, nScanBlocks);
    scanC_kernel<<<nScanBlocks, 256, 0, stream>>>(deg, blockSums, rowptr, cursor, N, E);
    fill_kernel<<<(E + 255) / 256, 256, 0, stream>>>(src, dst, cursor, srcs, E);

    agg1_kernel<<<(N * 64 + 255) / 256, 256, 0, stream>>>(h1b, rowptr, srcs, agg1b, N);

    gemm2_kernel<<<(N * 5 + 255) / 256, 256, 0, stream>>>(agg1b, W2, h2b, N);
    agg2_lsm_kernel<<<(N * 64 + 255) / 256, 256, 0, stream>>>(h2b, rowptr, srcs, out, N);
}